// Round 28
// baseline (143.707 us; speedup 1.0000x reference)
//
#include <hip/hip_runtime.h>
#include <hip/hip_bf16.h>
#include <stdint.h>

#define B_ 2
#define S_ 2048
#define H_ 32
#define D_ 128
#define R_ (B_*H_*S_)           // 131072 (b,h,s) rows
#define PG 2048                 // prep grid size

typedef __bf16 bf16x8 __attribute__((ext_vector_type(8)));
typedef float  f32x16 __attribute__((ext_vector_type(16)));

#if __has_builtin(__builtin_amdgcn_exp2f)
#define EXP2F(x) __builtin_amdgcn_exp2f(x)
#else
#define EXP2F(x) exp2f(x)
#endif

__device__ __forceinline__ unsigned short f2bf(float f) {
  unsigned u = __float_as_uint(f);
  u += 0x7FFFu + ((u >> 16) & 1u);
  return (unsigned short)(u >> 16);
}

__device__ __forceinline__ unsigned int cvtpk(float a, float b) {
  unsigned int r;
  asm("v_cvt_pk_bf16_f32 %0, %1, %2" : "=v"(r) : "v"(a), "v"(b));
  return r;
}

// Prep: q fp32 -> qc bf16 (scale*log2e folded; Q is now the 16x-re-read
// operand so IT gets the bf16 buffer); vsum = sum_d v; zero out scalar.
// K stays fp32 (read ~1.3x by attn). Footprint q+k+v+qc+nd = 240MB < L3.
__global__ __launch_bounds__(256) void prep(
    const float* __restrict__ qf, const float* __restrict__ v,
    unsigned short* __restrict__ qc,
    float* __restrict__ vsum, float* __restrict__ out0) {
  const int bid = blockIdx.x;
  const int t = threadIdx.x;
  if (bid == 0 && t == 0) out0[0] = 0.f;
  const float sc = 0.0883883476483184f * 1.4426950408889634f;

  #pragma unroll
  for (int g = 0; g < 4; ++g) {                 // q: 4 ushort8-units/thread
    const size_t i = (size_t)g * (PG * 256) + (size_t)bid * 256 + t;
    const float4 a = *reinterpret_cast<const float4*>(qf + i * 8);
    const float4 b = *reinterpret_cast<const float4*>(qf + i * 8 + 4);
    union { unsigned short u[8]; uint4 v4; } o;
    o.u[0] = f2bf(a.x * sc); o.u[1] = f2bf(a.y * sc);
    o.u[2] = f2bf(a.z * sc); o.u[3] = f2bf(a.w * sc);
    o.u[4] = f2bf(b.x * sc); o.u[5] = f2bf(b.y * sc);
    o.u[6] = f2bf(b.z * sc); o.u[7] = f2bf(b.w * sc);
    *reinterpret_cast<uint4*>(qc + i * 8) = o.v4;
  }

  #pragma unroll
  for (int g = 0; g < (B_ * S_) / PG; ++g) {    // vsum: 2 panels/block
    const int u = bid + g * PG;
    const int b = u / S_, s = u % S_;
    const float4* panel =
        reinterpret_cast<const float4*>(v + (((size_t)b * S_ + s) * H_) * D_);
    #pragma unroll
    for (int j = 0; j < 4; ++j) {
      const float4 a = panel[j * 256 + t];
      float sum = a.x + a.y + a.z + a.w;
      sum += __shfl_xor(sum, 1);
      sum += __shfl_xor(sum, 2);
      sum += __shfl_xor(sum, 4);
      sum += __shfl_xor(sum, 8);
      sum += __shfl_xor(sum, 16);
      const int h = j * 8 + (t >> 5);
      if ((t & 31) == 0) vsum[((size_t)b * H_ + h) * S_ + s] = sum;
    }
  }
}

// Main: BARRIER-FREE, LDS-FREE, wave-independent (the barrier'd-phase
// skeleton pinned at 79us across 6 falsified scheduling theories; warm
// replay at 3.5MB HBM ran identically -> structural, not memory). Each
// wave owns uniform k-major chunks of (kb64, qp64) pairs: K-block (64
// rows) register-resident as MFMA A-frags (cvt from fp32 once per kb-run);
// Q-pair (64 cols) streamed from bf16 qc; swapped mfma(K,Q) -> lane owns
// one q-column. Output: packed-bf16 (num,den) partial per (kb,side) slot
// in a triangular buffer -- NO atomics, plain stores; finalize sums <=32
// partials per q-row.
__global__ __launch_bounds__(256, 2) void attn_sum(
    const unsigned short* __restrict__ qc, const float* __restrict__ kf_,
    const float* __restrict__ vsum, unsigned int* __restrict__ ndu) {
  const int id   = blockIdx.x;           // 1024 blocks
  const int rest = id >> 3;              // 0..127
  const int bh   = (id & 7) + 8 * (rest >> 4);
  const int cp   = rest & 15;

  const int t = threadIdx.x;
  const int w = t >> 6, l = t & 63;
  const int ln = l & 31, l5 = l >> 5;
  const int chunk = cp * 4 + w;          // 0..63, per-wave

  // pair enumeration: for kb=0..31, qp=kb..31; prefix(kb)=32kb-kb(kb-1)/2.
  const int f0 = (chunk * 528) >> 6;
  const int f1 = ((chunk + 1) * 528) >> 6;
  int kb = 0;
  while (32 * (kb + 1) - ((kb + 1) * kb) / 2 <= f0) ++kb;
  int qp = kb + (f0 - (32 * kb - (kb * (kb - 1)) / 2));

  const int b0 = bh >> 5, h0 = bh & 31;
  const float* kbase = kf_ + ((size_t)b0 * S_ * H_ + h0) * D_;
  const unsigned short* qbase = qc + ((size_t)b0 * S_ * H_ + h0) * D_;
  const float* vbase = vsum + (size_t)bh * S_;
  unsigned int* ndb = ndu + (size_t)bh * 32 * 2048;

  bf16x8 kfr[2][8];
  float vsv[2][16];
  bool needK = true;

  for (int f = f0; f < f1; ++f) {
    if (needK) {   // load K-block (64 rows fp32 -> bf16 frags) + vsv
      #pragma unroll
      for (int nb = 0; nb < 2; ++nb) {
        const float* rp = kbase + (size_t)(kb * 64 + nb * 32 + ln) * (H_ * D_) + l5 * 8;
        #pragma unroll
        for (int c8 = 0; c8 < 8; ++c8) {
          const float4 a = *reinterpret_cast<const float4*>(rp + c8 * 16);
          const float4 b = *reinterpret_cast<const float4*>(rp + c8 * 16 + 4);
          union { unsigned int u[4]; bf16x8 v; } o;
          o.u[0] = cvtpk(a.x, a.y); o.u[1] = cvtpk(a.z, a.w);
          o.u[2] = cvtpk(b.x, b.y); o.u[3] = cvtpk(b.z, b.w);
          kfr[nb][c8] = o.v;
        }
        const float* vp = vbase + kb * 64 + nb * 32 + l5 * 4;
        const float4 v0 = *reinterpret_cast<const float4*>(vp);
        const float4 v1 = *reinterpret_cast<const float4*>(vp + 8);
        const float4 v2 = *reinterpret_cast<const float4*>(vp + 16);
        const float4 v3 = *reinterpret_cast<const float4*>(vp + 24);
        vsv[nb][ 0]=v0.x; vsv[nb][ 1]=v0.y; vsv[nb][ 2]=v0.z; vsv[nb][ 3]=v0.w;
        vsv[nb][ 4]=v1.x; vsv[nb][ 5]=v1.y; vsv[nb][ 6]=v1.z; vsv[nb][ 7]=v1.w;
        vsv[nb][ 8]=v2.x; vsv[nb][ 9]=v2.y; vsv[nb][10]=v2.z; vsv[nb][11]=v2.w;
        vsv[nb][12]=v3.x; vsv[nb][13]=v3.y; vsv[nb][14]=v3.z; vsv[nb][15]=v3.w;
      }
      needK = false;
    }

    // Q-pair: sides A (cols qp*64+ln) and B (+32).
    bf16x8 qfA[8], qfB[8];
    {
      const unsigned short* qA = qbase + (size_t)(qp * 64 + ln) * (H_ * D_) + l5 * 8;
      const unsigned short* qB = qA + (size_t)32 * (H_ * D_);
      #pragma unroll
      for (int c8 = 0; c8 < 8; ++c8) {
        qfA[c8] = *reinterpret_cast<const bf16x8*>(qA + c8 * 16);
        qfB[c8] = *reinterpret_cast<const bf16x8*>(qB + c8 * 16);
      }
    }

    const bool diag = (kb == qp);
    float npA = 0.f, dpA = 0.f, npB = 0.f, dpB = 0.f;

    // ---- side A, nb0 (diag: masked; nb1 fully masked when diag) ----
    {
      f32x16 s = {0.f,0.f,0.f,0.f,0.f,0.f,0.f,0.f,
                  0.f,0.f,0.f,0.f,0.f,0.f,0.f,0.f};
      #pragma unroll
      for (int c8 = 0; c8 < 8; ++c8)
        s = __builtin_amdgcn_mfma_f32_32x32x16_bf16(kfr[0][c8], qfA[c8], s, 0, 0, 0);
      if (diag) {
        const int qg = qp * 64 + ln;
        #pragma unroll
        for (int r = 0; r < 16; ++r) {
          const int kr = kb * 64 + (r & 3) + 8 * (r >> 2) + 4 * l5;
          const float e = (kr <= qg) ? EXP2F(s[r]) : 0.f;
          dpA += e; npA = fmaf(e, vsv[0][r], npA);
        }
      } else {
        #pragma unroll
        for (int r = 0; r < 16; ++r) {
          const float e = EXP2F(s[r]);
          dpA += e; npA = fmaf(e, vsv[0][r], npA);
        }
      }
    }
    if (!diag) {   // side A, nb1
      f32x16 s = {0.f,0.f,0.f,0.f,0.f,0.f,0.f,0.f,
                  0.f,0.f,0.f,0.f,0.f,0.f,0.f,0.f};
      #pragma unroll
      for (int c8 = 0; c8 < 8; ++c8)
        s = __builtin_amdgcn_mfma_f32_32x32x16_bf16(kfr[1][c8], qfA[c8], s, 0, 0, 0);
      #pragma unroll
      for (int r = 0; r < 16; ++r) {
        const float e = EXP2F(s[r]);
        dpA += e; npA = fmaf(e, vsv[1][r], npA);
      }
    }
    // ---- side B, nb0 (always full) ----
    {
      f32x16 s = {0.f,0.f,0.f,0.f,0.f,0.f,0.f,0.f,
                  0.f,0.f,0.f,0.f,0.f,0.f,0.f,0.f};
      #pragma unroll
      for (int c8 = 0; c8 < 8; ++c8)
        s = __builtin_amdgcn_mfma_f32_32x32x16_bf16(kfr[0][c8], qfB[c8], s, 0, 0, 0);
      #pragma unroll
      for (int r = 0; r < 16; ++r) {
        const float e = EXP2F(s[r]);
        dpB += e; npB = fmaf(e, vsv[0][r], npB);
      }
    }
    // ---- side B, nb1 (diag: masked) ----
    {
      f32x16 s = {0.f,0.f,0.f,0.f,0.f,0.f,0.f,0.f,
                  0.f,0.f,0.f,0.f,0.f,0.f,0.f,0.f};
      #pragma unroll
      for (int c8 = 0; c8 < 8; ++c8)
        s = __builtin_amdgcn_mfma_f32_32x32x16_bf16(kfr[1][c8], qfB[c8], s, 0, 0, 0);
      if (diag) {
        const int qg = qp * 64 + 32 + ln;
        #pragma unroll
        for (int r = 0; r < 16; ++r) {
          const int kr = kb * 64 + 32 + (r & 3) + 8 * (r >> 2) + 4 * l5;
          const float e = (kr <= qg) ? EXP2F(s[r]) : 0.f;
          dpB += e; npB = fmaf(e, vsv[1][r], npB);
        }
      } else {
        #pragma unroll
        for (int r = 0; r < 16; ++r) {
          const float e = EXP2F(s[r]);
          dpB += e; npB = fmaf(e, vsv[1][r], npB);
        }
      }
    }

    // Combine l5 halves; one packed-bf16 store per side (no atomics).
    npA += __shfl_xor(npA, 32); dpA += __shfl_xor(dpA, 32);
    npB += __shfl_xor(npB, 32); dpB += __shfl_xor(dpB, 32);
    if (l5 == 0) {
      unsigned int* row = ndb + (size_t)kb * 2048 + qp * 64;
      row[ln]      = cvtpk(npA, dpA);   // lo=num, hi=den
      row[32 + ln] = cvtpk(npB, dpB);
    }

    ++qp;
    if (qp == 32) { ++kb; qp = kb; needK = true; }
  }
}

// Finalize: per q-row, sum <=32 packed-bf16 partials, divide, reduce.
__global__ __launch_bounds__(256) void finalize(
    const unsigned int* __restrict__ ndu, float* __restrict__ out) {
  const int r = blockIdx.x * 256 + threadIdx.x;   // 0..131071
  const int bh = r >> 11, q = r & 2047;
  const int qp = q >> 6;
  const unsigned int* p = ndu + (size_t)bh * 32 * 2048 + q;
  float np = 0.f, dp = 0.f;
  for (int kb = 0; kb <= qp; ++kb) {
    const unsigned int u = p[(size_t)kb * 2048];
    np += __uint_as_float(u << 16);
    dp += __uint_as_float(u & 0xffff0000u);
  }
  float c = np / dp;
  #pragma unroll
  for (int m = 1; m < 64; m <<= 1) c += __shfl_xor(c, m);
  __shared__ float ps[4];
  if ((threadIdx.x & 63) == 0) ps[threadIdx.x >> 6] = c;
  __syncthreads();
  if (threadIdx.x == 0) atomicAdd(out, ps[0] + ps[1] + ps[2] + ps[3]);
}

extern "C" void kernel_launch(void* const* d_in, const int* in_sizes, int n_in,
                              void* d_out, int out_size, void* d_ws, size_t ws_size,
                              hipStream_t stream) {
  const float* q = (const float*)d_in[0];
  const float* k = (const float*)d_in[1];
  const float* v = (const float*)d_in[2];
  float* out = (float*)d_out;

  unsigned short* qc = (unsigned short*)d_ws;                 // 32 MiB
  float* vsum = (float*)(qc + (size_t)R_ * D_);               // 512 KiB
  unsigned int* ndu = (unsigned int*)(vsum + R_);             // 16.8 MiB

  hipLaunchKernelGGL(prep, dim3(PG), dim3(256), 0, stream,
                     q, v, qc, vsum, out);
  hipLaunchKernelGGL(attn_sum, dim3(1024), dim3(256), 0, stream,
                     qc, k, vsum, ndu);
  hipLaunchKernelGGL(finalize, dim3(R_ / 256), dim3(256), 0, stream,
                     ndu, out);
}

// Round 29
// 108.008 us; speedup vs baseline: 1.3305x; 1.3305x over previous
//
#include <hip/hip_runtime.h>
#include <hip/hip_bf16.h>
#include <stdint.h>

#define B_ 2
#define S_ 2048
#define H_ 32
#define D_ 128
#define R_ (B_*H_*S_)           // 131072 (b,h,s) rows
#define PG 2048                 // prep grid size
#define CPB 36                  // UNIFORM 4-tile chunks per bh: sum_{g=0..7}(g+1)

typedef __bf16 bf16x8 __attribute__((ext_vector_type(8)));
typedef float  f32x16 __attribute__((ext_vector_type(16)));

#if __has_builtin(__builtin_amdgcn_exp2f)
#define EXP2F(x) __builtin_amdgcn_exp2f(x)
#else
#define EXP2F(x) exp2f(x)
#endif

#define AS1 __attribute__((address_space(1)))
#define AS3 __attribute__((address_space(3)))

__device__ __forceinline__ unsigned short f2bf(float f) {
  unsigned u = __float_as_uint(f);
  u += 0x7FFFu + ((u >> 16) & 1u);
  return (unsigned short)(u >> 16);
}

__device__ __forceinline__ unsigned int cvtpk(float a, float b) {
  unsigned int r;
  asm("v_cvt_pk_bf16_f32 %0, %1, %2" : "=v"(r) : "v"(a), "v"(b));
  return r;
}

// Prep (R21-identical): K convert only (+vsum+zeroing). Footprint:
// q+k+v+kc = 224MB < 256MB L3 -> replay traffic L3-served.
__global__ __launch_bounds__(256) void prep(
    const float* __restrict__ kf, const float* __restrict__ v,
    unsigned short* __restrict__ kc,
    float* __restrict__ vsum, float* __restrict__ nd, float* __restrict__ out0) {
  const int bid = blockIdx.x;
  const int t = threadIdx.x;
  if (bid == 0 && t == 0) out0[0] = 0.f;

  #pragma unroll
  for (int g = 0; g < 4; ++g) {                 // k: 4 ushort8-units/thread
    const size_t i = (size_t)g * (PG * 256) + (size_t)bid * 256 + t;
    const float4 a = *reinterpret_cast<const float4*>(kf + i * 8);
    const float4 b = *reinterpret_cast<const float4*>(kf + i * 8 + 4);
    union { unsigned short u[8]; uint4 v4; } o;
    o.u[0] = f2bf(a.x); o.u[1] = f2bf(a.y);
    o.u[2] = f2bf(a.z); o.u[3] = f2bf(a.w);
    o.u[4] = f2bf(b.x); o.u[5] = f2bf(b.y);
    o.u[6] = f2bf(b.z); o.u[7] = f2bf(b.w);
    *reinterpret_cast<uint4*>(kc + i * 8) = o.v4;
  }

  #pragma unroll
  for (int g = 0; g < (B_ * S_) / PG; ++g) {    // vsum: 2 panels/block
    const int u = bid + g * PG;
    const int b = u / S_, s = u % S_;
    const float4* panel =
        reinterpret_cast<const float4*>(v + (((size_t)b * S_ + s) * H_) * D_);
    #pragma unroll
    for (int j = 0; j < 4; ++j) {
      const float4 a = panel[j * 256 + t];
      float sum = a.x + a.y + a.z + a.w;
      sum += __shfl_xor(sum, 1);
      sum += __shfl_xor(sum, 2);
      sum += __shfl_xor(sum, 4);
      sum += __shfl_xor(sum, 8);
      sum += __shfl_xor(sum, 16);
      const int h = j * 8 + (t >> 5);           // 32-lane group owns one h-row
      if ((t & 31) == 0) vsum[((size_t)b * H_ + h) * S_ + s] = sum;
    }
  }

  if (bid < 256) {
    float4* p = reinterpret_cast<float4*>(nd);
    p[(size_t)bid * 256 + t] = float4{0.f, 0.f, 0.f, 0.f};
  }
}

// Main (R26-exact compute/pipeline; ONE change: UNIFORM partition). R26's
// counters showed time-avg ~2 blocks/CU vs 6-block capacity: grid 1728
// (6.75/CU, bad quantization), per-block work 2-12 subtiles, light blocks
// dispatched first -> heavy-tail on an idle machine. Fix: pair g's
// nkt = 4(g+1) tiles splits into EXACTLY (g+1) 4-tile chunks -> every block
// does exactly 8 subtiles; CPB=36, grid 2304 = 9/CU. Ring-3, depth-2,
// counted vmcnt(3), raw s_barrier, XOR-involution DMA, swapped mfma(K,Q),
// fp32 Q + cvt_pk -- all unchanged.
__global__ __launch_bounds__(256, 3) void attn_sum(
    const float* __restrict__ qf, const unsigned short* __restrict__ kc,
    const float* __restrict__ vsum, float* __restrict__ numb,
    float* __restrict__ denb) {
  __shared__ uint4 kbuf[3][512];       // 3 x 8KB
  __shared__ float vsbuf[3][64];       // 3 x 256B

  const int id = blockIdx.x;
  const int y  = id >> 3;
  const int bh = (id & 7) + 8 * (y / CPB);
  const int c  = y % CPB;

  // uniform table: pair g has (g+1) chunks; prefix T(g)=g(g+1)/2.
  int g, h;
  if (c < 1)       { g = 0; h = c;      }
  else if (c < 3)  { g = 1; h = c - 1;  }
  else if (c < 6)  { g = 2; h = c - 3;  }
  else if (c < 10) { g = 3; h = c - 6;  }
  else if (c < 15) { g = 4; h = c - 10; }
  else if (c < 21) { g = 5; h = c - 15; }
  else if (c < 28) { g = 6; h = c - 21; }
  else             { g = 7; h = c - 28; }
  const int st0 = 8 * h, st1 = st0 + 8;    // exactly 8 32-row subtiles

  const int t  = threadIdx.x;
  const int w  = t >> 6;
  const int l  = t & 63;
  const int ln = l & 31, l5 = l >> 5;

  const int b0 = bh >> 5, h0 = bh & 31;
  const int qminA = (2 * g) * 128 + w * 32;
  const int qminB = (2 * g + 1) * 128 + w * 32;
  const unsigned short* kc0 = kc + ((size_t)b0 * S_ * H_ + h0) * D_;
  const float* vsrc0 = vsum + (size_t)bh * S_;

  // Q B-frags for both tiles from fp32 (scale*log2e folded), once per block.
  const float sc = 0.0883883476483184f * 1.4426950408889634f;
  bf16x8 qfA[8], qfB[8];
  {
    const float* qpA = qf + (((size_t)b0 * S_ + qminA + ln) * H_ + h0) * D_ + l5 * 8;
    const float* qpB = qf + (((size_t)b0 * S_ + qminB + ln) * H_ + h0) * D_ + l5 * 8;
    #pragma unroll
    for (int kb8 = 0; kb8 < 8; ++kb8) {
      float4 a = *reinterpret_cast<const float4*>(qpA + kb8 * 16);
      float4 b = *reinterpret_cast<const float4*>(qpA + kb8 * 16 + 4);
      union { unsigned int u[4]; bf16x8 v; } oA;
      oA.u[0] = cvtpk(a.x * sc, a.y * sc); oA.u[1] = cvtpk(a.z * sc, a.w * sc);
      oA.u[2] = cvtpk(b.x * sc, b.y * sc); oA.u[3] = cvtpk(b.z * sc, b.w * sc);
      qfA[kb8] = oA.v;
      a = *reinterpret_cast<const float4*>(qpB + kb8 * 16);
      b = *reinterpret_cast<const float4*>(qpB + kb8 * 16 + 4);
      union { unsigned int u[4]; bf16x8 v; } oB;
      oB.u[0] = cvtpk(a.x * sc, a.y * sc); oB.u[1] = cvtpk(a.z * sc, a.w * sc);
      oB.u[2] = cvtpk(b.x * sc, b.y * sc); oB.u[3] = cvtpk(b.z * sc, b.w * sc);
      qfB[kb8] = oB.v;
    }
  }

  // Stage one 32-row subtile: 2 K-DMAs + 1 vsum-DMA = 3 vmcnt ops.
  auto stage = [&](int st, int slot) {
    #pragma unroll
    for (int j = 0; j < 2; ++j) {
      const int idx = (w * 2 + j) * 64 + l;   // physical 16B slot in subtile
      const int r   = idx >> 4;
      const int p   = idx & 15;
      const int cc  = p ^ (r & 15);           // logical chunk stored here
      const unsigned short* src = kc0 + (size_t)(st * 32 + r) * (H_ * D_) + cc * 8;
      __builtin_amdgcn_global_load_lds(
          (const AS1 void*)src, (AS3 void*)(&kbuf[slot][idx & ~63]), 16, 0, 0);
    }
    __builtin_amdgcn_global_load_lds(
        (const AS1 void*)(vsrc0 + st * 32 + l), (AS3 void*)(&vsbuf[slot][0]), 4, 0, 0);
  };

  float npA = 0.f, dpA = 0.f, npB = 0.f, dpB = 0.f;

  // Prologue: depth-2 into ring-3.
  stage(st0, st0 % 3);
  stage(st0 + 1, (st0 + 1) % 3);

  const int xr = ln & 15;
  for (int st = st0; st < st1; ++st) {
    if (st + 1 < st1) asm volatile("s_waitcnt vmcnt(3)" ::: "memory");
    else              asm volatile("s_waitcnt vmcnt(0)" ::: "memory");
    __builtin_amdgcn_s_barrier();            // raw: batch st+1 stays in flight
    if (st + 2 < st1) stage(st + 2, (st + 2) % 3);   // ring-3-safe slot

    const int kbase = st * 32;
    if (kbase <= qminB + 31) {               // B active (A-active implies this)
      const int slot = st % 3;
      const uint4* rowb = &kbuf[slot][ln * 16];
      bf16x8 kfr[8];
      #pragma unroll
      for (int kb8 = 0; kb8 < 8; ++kb8)
        kfr[kb8] = *reinterpret_cast<const bf16x8*>(&rowb[(kb8 * 2 + l5) ^ xr]);
      const float4 vs0 = *reinterpret_cast<const float4*>(&vsbuf[slot][ 0 + 4 * l5]);
      const float4 vs1 = *reinterpret_cast<const float4*>(&vsbuf[slot][ 8 + 4 * l5]);
      const float4 vs2 = *reinterpret_cast<const float4*>(&vsbuf[slot][16 + 4 * l5]);
      const float4 vs3 = *reinterpret_cast<const float4*>(&vsbuf[slot][24 + 4 * l5]);
      const float vsa[16] = {vs0.x,vs0.y,vs0.z,vs0.w, vs1.x,vs1.y,vs1.z,vs1.w,
                             vs2.x,vs2.y,vs2.z,vs2.w, vs3.x,vs3.y,vs3.z,vs3.w};

      // ---- side B ----
      {
        f32x16 sacc = {0.f,0.f,0.f,0.f,0.f,0.f,0.f,0.f,
                       0.f,0.f,0.f,0.f,0.f,0.f,0.f,0.f};
        __builtin_amdgcn_s_setprio(1);
        #pragma unroll
        for (int kb8 = 0; kb8 < 8; ++kb8)
          sacc = __builtin_amdgcn_mfma_f32_32x32x16_bf16(kfr[kb8], qfB[kb8], sacc, 0, 0, 0);
        __builtin_amdgcn_s_setprio(0);
        if (kbase + 31 <= qminB) {
          #pragma unroll
          for (int r = 0; r < 16; ++r) {
            const float e = EXP2F(sacc[r]);
            dpB += e;
            npB = fmaf(e, vsa[r], npB);
          }
        } else {
          const int qg = qminB + ln;
          #pragma unroll
          for (int r = 0; r < 16; ++r) {
            const int kr = kbase + (r & 3) + 8 * (r >> 2) + 4 * l5;
            const float e = (kr <= qg) ? EXP2F(sacc[r]) : 0.f;
            dpB += e;
            npB = fmaf(e, vsa[r], npB);
          }
        }
      }
      // ---- side A ----
      if (kbase <= qminA + 31) {
        f32x16 sacc = {0.f,0.f,0.f,0.f,0.f,0.f,0.f,0.f,
                       0.f,0.f,0.f,0.f,0.f,0.f,0.f,0.f};
        __builtin_amdgcn_s_setprio(1);
        #pragma unroll
        for (int kb8 = 0; kb8 < 8; ++kb8)
          sacc = __builtin_amdgcn_mfma_f32_32x32x16_bf16(kfr[kb8], qfA[kb8], sacc, 0, 0, 0);
        __builtin_amdgcn_s_setprio(0);
        if (kbase + 31 <= qminA) {
          #pragma unroll
          for (int r = 0; r < 16; ++r) {
            const float e = EXP2F(sacc[r]);
            dpA += e;
            npA = fmaf(e, vsa[r], npA);
          }
        } else {
          const int qg = qminA + ln;
          #pragma unroll
          for (int r = 0; r < 16; ++r) {
            const int kr = kbase + (r & 3) + 8 * (r >> 2) + 4 * l5;
            const float e = (kr <= qg) ? EXP2F(sacc[r]) : 0.f;
            dpA += e;
            npA = fmaf(e, vsa[r], npA);
          }
        }
      }
    }
  }

  // Combine l5 halves (same q-col, disjoint k-rows); 2 atomic pairs per col.
  npA += __shfl_xor(npA, 32); dpA += __shfl_xor(dpA, 32);
  npB += __shfl_xor(npB, 32); dpB += __shfl_xor(dpB, 32);
  if (l5 == 0) {
    float* nrow = numb + (size_t)bh * S_;
    float* drow = denb + (size_t)bh * S_;
    atomicAdd(&nrow[qminA + ln], npA);
    atomicAdd(&drow[qminA + ln], dpA);
    atomicAdd(&nrow[qminB + ln], npB);
    atomicAdd(&drow[qminB + ln], dpB);
  }
}

// Finalize: sum(num/den) over all q-rows.
__global__ __launch_bounds__(256) void finalize(
    const float* __restrict__ numb, const float* __restrict__ denb,
    float* __restrict__ out) {
  const int i = blockIdx.x * 256 + threadIdx.x;
  float c = numb[i] / denb[i];
  #pragma unroll
  for (int m = 1; m < 64; m <<= 1) c += __shfl_xor(c, m);
  __shared__ float ps[4];
  if ((threadIdx.x & 63) == 0) ps[threadIdx.x >> 6] = c;
  __syncthreads();
  if (threadIdx.x == 0) atomicAdd(out, ps[0] + ps[1] + ps[2] + ps[3]);
}

extern "C" void kernel_launch(void* const* d_in, const int* in_sizes, int n_in,
                              void* d_out, int out_size, void* d_ws, size_t ws_size,
                              hipStream_t stream) {
  const float* q = (const float*)d_in[0];
  const float* k = (const float*)d_in[1];
  const float* v = (const float*)d_in[2];
  float* out = (float*)d_out;

  unsigned short* kc = (unsigned short*)d_ws;                 // 32 MiB
  float* vsum = (float*)(kc + (size_t)R_ * D_);               // 512 KiB
  float* numb = vsum + R_;                                    // 512 KiB
  float* denb = numb + R_;                                    // 512 KiB

  hipLaunchKernelGGL(prep, dim3(PG), dim3(256), 0, stream,
                     k, v, kc, vsum, numb, out);
  hipLaunchKernelGGL(attn_sum, dim3(64 * CPB), dim3(256), 0, stream,
                     q, kc, vsum, numb, denb);
  hipLaunchKernelGGL(finalize, dim3(R_ / 256), dim3(256), 0, stream,
                     numb, denb, out);
}